// Round 15
// baseline (75.485 us; speedup 1.0000x reference)
//
#include <hip/hip_runtime.h>

#define T_STEPS 100
#define BATCH 256
#define NIN 784
#define N0 64
#define N1 64
#define N2 10
#define CHUNK (BATCH*N0 + BATCH*N1 + BATCH*N2)   // 35328
#define NCHUNKS 49                               // 784 / 16
#define PLANE (BATCH*T_STEPS*64)                 // partial plane (floats), b-major
#define BM 64                                    // gemm0 tile rows

#define FMA4(d, s, v) \
  d.x = fmaf((s), (v).x, d.x); d.y = fmaf((s), (v).y, d.y); \
  d.z = fmaf((s), (v).z, d.z); d.w = fmaf((s), (v).w, d.w;)

#undef FMA4
#define FMA4(d, s, v) \
  d.x = fmaf((s), (v).x, d.x); d.y = fmaf((s), (v).y, d.y); \
  d.z = fmaf((s), (v).z, d.z); d.w = fmaf((s), (v).w, d.w);

// ---------------------------------------------------------------------------
// Kernel 1: partial I0 = X @ W0^T. Tile 64x64, 128 threads, micro-tile 8x4
// (0.75 B LDS per FLOP, acc = 32 VGPR). Double-buffered LDS, 1 sync/chunk.
// K-split over blockIdx.y (nsplit runtime, 8 -> chunks {7,6x7}).
// Output b-major P[s][b][t][j] (tile lies in a single t). 3200 blocks ->
// 6400 waves: grid no longer limits occupancy (R7's failure mode).
// ---------------------------------------------------------------------------
__global__ __launch_bounds__(128, 4) void gemm0_kernel(
    const float* __restrict__ X, const float* __restrict__ W0,
    float* __restrict__ P, int nsplit) {
  __shared__ float As[2][16][68];   // [buf][k][row]
  __shared__ float Bs[2][16][68];   // [buf][k][col]

  const int tid = threadIdx.x;
  const int r0  = blockIdx.x * BM;
  const int s   = blockIdx.y;
  const int tn  = tid & 15;          // cols tn*4..+3
  const int tm  = tid >> 4;          // row-group 0..7: rows tm*8..+7

  const int per  = NCHUNKS / nsplit;
  const int rem  = NCHUNKS % nsplit;
  const int cbeg = s * per + (s < rem ? s : rem);
  const int ccnt = per + (s < rem ? 1 : 0);

  float4 acc[8];                     // acc[i] = cols tn*4..+3 of row tm*8+i
#pragma unroll
  for (int i = 0; i < 8; ++i) acc[i] = float4{0.f, 0.f, 0.f, 0.f};

  // staging: A/B each 256 f4 per fill; 128 threads -> 2 f4 each
  const int arow = tid >> 2;         // 0..31 (+32 for second)
  const int akq  = tid & 3;          // k-quad

  const float* xbase = X  + (size_t)cbeg * 16 + akq * 4;
  const float* wbase = W0 + (size_t)cbeg * 16 + akq * 4;

  // prologue: chunk 0 -> buffer 0
  {
#pragma unroll
    for (int i = 0; i < 2; ++i) {
      int row = arow + i * 32;
      float4 xv = *(const float4*)(xbase + (size_t)(r0 + row) * NIN);
      As[0][akq*4+0][row] = xv.x;
      As[0][akq*4+1][row] = xv.y;
      As[0][akq*4+2][row] = xv.z;
      As[0][akq*4+3][row] = xv.w;
      float4 wv = *(const float4*)(wbase + (size_t)row * NIN);
      Bs[0][akq*4+0][row] = wv.x;
      Bs[0][akq*4+1][row] = wv.y;
      Bs[0][akq*4+2][row] = wv.z;
      Bs[0][akq*4+3][row] = wv.w;
    }
  }
  __syncthreads();

  for (int c = 0; c < ccnt; ++c) {
    const int cur = c & 1;
    float4 xa[2], wb[2];
    const bool more = (c + 1 < ccnt);
    if (more) {                      // issue next-chunk loads BEFORE compute
#pragma unroll
      for (int i = 0; i < 2; ++i) {
        int row = arow + i * 32;
        xa[i] = *(const float4*)(xbase + (size_t)(r0 + row) * NIN + (c + 1) * 16);
        wb[i] = *(const float4*)(wbase + (size_t)row * NIN + (c + 1) * 16);
      }
    }
#pragma unroll 4
    for (int k = 0; k < 16; ++k) {
      float4 a0 = *(const float4*)&As[cur][k][tm * 8];
      float4 a1 = *(const float4*)&As[cur][k][tm * 8 + 4];
      float4 b  = *(const float4*)&Bs[cur][k][tn * 4];
      FMA4(acc[0], a0.x, b);
      FMA4(acc[1], a0.y, b);
      FMA4(acc[2], a0.z, b);
      FMA4(acc[3], a0.w, b);
      FMA4(acc[4], a1.x, b);
      FMA4(acc[5], a1.y, b);
      FMA4(acc[6], a1.z, b);
      FMA4(acc[7], a1.w, b);
    }
    if (more) {                      // write prefetched chunk to OTHER buffer
      const int nxt = cur ^ 1;
#pragma unroll
      for (int i = 0; i < 2; ++i) {
        int row = arow + i * 32;
        As[nxt][akq*4+0][row] = xa[i].x;
        As[nxt][akq*4+1][row] = xa[i].y;
        As[nxt][akq*4+2][row] = xa[i].z;
        As[nxt][akq*4+3][row] = xa[i].w;
        Bs[nxt][akq*4+0][row] = wb[i].x;
        Bs[nxt][akq*4+1][row] = wb[i].y;
        Bs[nxt][akq*4+2][row] = wb[i].z;
        Bs[nxt][akq*4+3][row] = wb[i].w;
      }
    }
    __syncthreads();
  }

  // epilogue: b-major write (whole tile shares one t since 64 | 256)
  const int t0  = r0 >> 8;
  const int bb0 = r0 & 255;
  float* op = P + (size_t)s * PLANE;
#pragma unroll
  for (int i = 0; i < 8; ++i) {
    const int bb = bb0 + tm * 8 + i;
    *(float4*)(op + ((size_t)bb * T_STEPS + t0) * 64 + tn * 4) = acc[i];
  }
}

// ---------------------------------------------------------------------------
// Kernel 2: one block per batch element. Staging sums nsplit b-major plane
// slabs (each contiguous 25.6 KB) + bias (ascending s, bias last), then
// scan0 -> GEMM1 -> scan1 -> GEMM2 -> scan2 (proven R7 body).
// ---------------------------------------------------------------------------
__global__ __launch_bounds__(256) void fused_kernel(
    const float* __restrict__ P, int nsplit, const float* __restrict__ b0,
    const float* __restrict__ W1, const float* __restrict__ b1,
    const float* __restrict__ W2, const float* __restrict__ b2,
    float* __restrict__ out) {
  __shared__ float bufA[112][68];
  __shared__ float sW1t[64][68];
  __shared__ float sW2[N2][68];
  __shared__ float sI2[T_STEPS][N2];

  const int b   = blockIdx.x;
  const int tid = threadIdx.x;
  const int j   = tid & 63;
  const int tq  = tid >> 6;
  float* outSpk = out;
  float* laySpk = out + T_STEPS * BATCH * N2;

  // ---- stage I0 = sum_s P[s][b] + b0
  {
    const float4* base = (const float4*)P + (size_t)b * (T_STEPS * 16);
    const size_t pstep = PLANE / 4;
    for (int idx = tid; idx < T_STEPS * 16; idx += 256) {
      float4 v = base[idx];
      for (int s = 1; s < nsplit; ++s) {
        float4 u = base[idx + (size_t)s * pstep];
        v.x += u.x; v.y += u.y; v.z += u.z; v.w += u.w;
      }
      int t = idx >> 4, j4 = idx & 15;
      float4 bv = ((const float4*)b0)[j4];
      v.x += bv.x; v.y += bv.y; v.z += bv.z; v.w += bv.w;
      *(float4*)&bufA[t][j4 * 4] = v;
    }
  }
  __syncthreads();

  // ---- scan0 (wave 0, batched) || W1/W2 staging (waves 1-3)
  if (tq == 0) {
    float v = 0.0f;
#pragma unroll
    for (int g = 0; g < 4; ++g) {
      float ic[25];
#pragma unroll
      for (int i = 0; i < 25; ++i) ic[i] = bufA[g * 25 + i][j];
#pragma unroll
      for (int i = 0; i < 25; ++i) {
        v = v + 0.05f * ((0.0f - v) + ic[i]);
        float z = (v > 1.0f) ? 1.0f : 0.0f;
        v -= z;
        ic[i] = z;
      }
#pragma unroll
      for (int i = 0; i < 25; ++i) bufA[g * 25 + i][j] = ic[i];
    }
  } else {
    for (int idx = tid - 64; idx < 64 * 16; idx += 192) {
      int i = idx >> 4, jv = idx & 15;
      float4 wv = *(const float4*)(W1 + (size_t)i * 64 + jv * 4);
      sW1t[jv * 4 + 0][i] = wv.x;
      sW1t[jv * 4 + 1][i] = wv.y;
      sW1t[jv * 4 + 2][i] = wv.z;
      sW1t[jv * 4 + 3][i] = wv.w;
    }
    for (int idx = tid - 64; idx < N2 * 16; idx += 192) {
      int o = idx >> 4, jv = idx & 15;
      *(float4*)&sW2[o][jv * 4] = *(const float4*)(W2 + (size_t)o * 64 + jv * 4);
    }
  }
  __syncthreads();

  // ---- z0 -> layer_spikes
  for (int idx = tid; idx < T_STEPS * 16; idx += 256) {
    int t = idx >> 4, jv = idx & 15;
    *(float4*)(laySpk + (size_t)t * CHUNK + b * 64 + jv * 4) =
        *(const float4*)&bufA[t][jv * 4];
  }

  // ---- GEMM1
  const int iq = tid & 15;
  const int ts = tid >> 4;
  float g1[4][7];
  {
    float4 bias = *(const float4*)(b1 + iq * 4);
#pragma unroll
    for (int tt = 0; tt < 7; ++tt) {
      g1[0][tt] = bias.x; g1[1][tt] = bias.y; g1[2][tt] = bias.z; g1[3][tt] = bias.w;
    }
#pragma unroll
    for (int jq = 0; jq < 16; ++jq) {
      float4 zv4[7];
#pragma unroll
      for (int tt = 0; tt < 7; ++tt)
        zv4[tt] = *(const float4*)&bufA[ts * 7 + tt][jq * 4];
      float4 w4[4];
#pragma unroll
      for (int e = 0; e < 4; ++e)
        w4[e] = *(const float4*)&sW1t[jq * 4 + e][iq * 4];
#pragma unroll
      for (int e = 0; e < 4; ++e) {
#pragma unroll
        for (int tt = 0; tt < 7; ++tt) {
          float zv = ((const float*)&zv4[tt])[e];
          g1[0][tt] = fmaf(zv, w4[e].x, g1[0][tt]);
          g1[1][tt] = fmaf(zv, w4[e].y, g1[1][tt]);
          g1[2][tt] = fmaf(zv, w4[e].z, g1[2][tt]);
          g1[3][tt] = fmaf(zv, w4[e].w, g1[3][tt]);
        }
      }
    }
  }
  __syncthreads();
#pragma unroll
  for (int tt = 0; tt < 7; ++tt) {
    float4 o = {g1[0][tt], g1[1][tt], g1[2][tt], g1[3][tt]};
    *(float4*)&bufA[ts * 7 + tt][iq * 4] = o;
  }
  __syncthreads();

  // ---- scan1
  if (tq == 0) {
    float v = 0.0f;
#pragma unroll
    for (int g = 0; g < 4; ++g) {
      float ic[25];
#pragma unroll
      for (int i = 0; i < 25; ++i) ic[i] = bufA[g * 25 + i][j];
#pragma unroll
      for (int i = 0; i < 25; ++i) {
        v = v + 0.05f * ((0.0f - v) + ic[i]);
        float z = (v > 1.0f) ? 1.0f : 0.0f;
        v -= z;
        ic[i] = z;
      }
#pragma unroll
      for (int i = 0; i < 25; ++i) bufA[g * 25 + i][j] = ic[i];
    }
  }
  __syncthreads();

  // ---- z1 -> layer_spikes
  for (int idx = tid; idx < T_STEPS * 16; idx += 256) {
    int t = idx >> 4, jv = idx & 15;
    *(float4*)(laySpk + (size_t)t * CHUNK + BATCH * N0 + b * 64 + jv * 4) =
        *(const float4*)&bufA[t][jv * 4];
  }

  // ---- GEMM2
  for (int idx = tid; idx < T_STEPS * N2; idx += 256) {
    int t = idx / N2, o = idx % N2;
    float a = b2[o];
#pragma unroll
    for (int jq = 0; jq < 16; ++jq) {
      float4 z = *(const float4*)&bufA[t][jq * 4];
      float4 wv = *(const float4*)&sW2[o][jq * 4];
      a += z.x * wv.x;
      a += z.y * wv.y;
      a += z.z * wv.z;
      a += z.w * wv.w;
    }
    sI2[t][o] = a;
  }
  __syncthreads();

  // ---- scan2
  if (tid < N2) {
    float v = 0.0f;
#pragma unroll
    for (int g = 0; g < 4; ++g) {
      float ic[25];
#pragma unroll
      for (int i = 0; i < 25; ++i) ic[i] = sI2[g * 25 + i][tid];
#pragma unroll
      for (int i = 0; i < 25; ++i) {
        v = v + 0.05f * ((0.0f - v) + ic[i]);
        float z = (v > 1.0f) ? 1.0f : 0.0f;
        v -= z;
        ic[i] = z;
      }
#pragma unroll
      for (int i = 0; i < 25; ++i) sI2[g * 25 + i][tid] = ic[i];
    }
  }
  __syncthreads();

  for (int idx = tid; idx < T_STEPS * N2; idx += 256) {
    int t = idx / N2, o = idx % N2;
    float z = sI2[t][o];
    outSpk[(size_t)t * (BATCH * N2) + b * N2 + o] = z;
    laySpk[(size_t)t * CHUNK + BATCH * (N0 + N1) + b * N2 + o] = z;
  }
}

extern "C" void kernel_launch(void* const* d_in, const int* in_sizes, int n_in,
                              void* d_out, int out_size, void* d_ws, size_t ws_size,
                              hipStream_t stream) {
  const float* inp = (const float*)d_in[0];
  const float* W0  = (const float*)d_in[1];
  const float* b0  = (const float*)d_in[2];
  const float* W1  = (const float*)d_in[3];
  const float* b1  = (const float*)d_in[4];
  const float* W2  = (const float*)d_in[5];
  const float* b2  = (const float*)d_in[6];

  const size_t plane_bytes = (size_t)PLANE * sizeof(float);   // 6.55 MB
  int nsplit = (ws_size >= 8 * plane_bytes) ? 8 :
               (ws_size >= 4 * plane_bytes) ? 4 : 2;

  float* P = (float*)d_ws;   // nsplit planes, b-major [s][b][t][j]

  gemm0_kernel<<<dim3(25600 / BM, nsplit), dim3(128), 0, stream>>>(inp, W0, P,
                                                                   nsplit);
  fused_kernel<<<dim3(BATCH), dim3(256), 0, stream>>>(P, nsplit, b0, W1, b1,
                                                      W2, b2, (float*)d_out);
}

// Round 16
// 71.802 us; speedup vs baseline: 1.0513x; 1.0513x over previous
//
#include <hip/hip_runtime.h>

#define T_STEPS 100
#define BATCH 256
#define NIN 784
#define N0 64
#define N1 64
#define N2 10
#define CHUNK (BATCH*N0 + BATCH*N1 + BATCH*N2)   // 35328
#define NCHUNKS 49                               // 784 / 16
#define NSPLIT 4
#define PLANE (BATCH*T_STEPS*64)                 // partial plane (floats), b-major
#define I0ELEMS (25600*64)
#define BM 64                                    // gemm0 tile rows

#define FMA4(d, s, v) \
  d.x = fmaf((s), (v).x, d.x); d.y = fmaf((s), (v).y, d.y); \
  d.z = fmaf((s), (v).z, d.z); d.w = fmaf((s), (v).w, d.w);

// ---------------------------------------------------------------------------
// Kernel 1: partial I0 = X @ W0^T. Tile 64x64, 128 threads, micro-tile 8x4
// (0.75 B LDS per FLOP). Double-buffered LDS, 1 sync/chunk. K-split over
// blockIdx.y with {13,12,12,12} chunks (R4/R7 association). Output b-major
// P[s][b][t][j]. (R15 kernel, measured 47-49 us.)
// ---------------------------------------------------------------------------
__global__ __launch_bounds__(128, 4) void gemm0_kernel(
    const float* __restrict__ X, const float* __restrict__ W0,
    float* __restrict__ P) {
  __shared__ float As[2][16][68];   // [buf][k][row]
  __shared__ float Bs[2][16][68];   // [buf][k][col]

  const int tid = threadIdx.x;
  const int r0  = blockIdx.x * BM;
  const int s   = blockIdx.y;
  const int tn  = tid & 15;          // cols tn*4..+3
  const int tm  = tid >> 4;          // row-group 0..7: rows tm*8..+7

  const int per  = NCHUNKS / NSPLIT;      // 12
  const int rem  = NCHUNKS % NSPLIT;      // 1
  const int cbeg = s * per + (s < rem ? s : rem);
  const int ccnt = per + (s < rem ? 1 : 0);

  float4 acc[8];
#pragma unroll
  for (int i = 0; i < 8; ++i) acc[i] = float4{0.f, 0.f, 0.f, 0.f};

  const int arow = tid >> 2;         // 0..31 (+32 for second)
  const int akq  = tid & 3;          // k-quad

  const float* xbase = X  + (size_t)cbeg * 16 + akq * 4;
  const float* wbase = W0 + (size_t)cbeg * 16 + akq * 4;

  // prologue: chunk 0 -> buffer 0
  {
#pragma unroll
    for (int i = 0; i < 2; ++i) {
      int row = arow + i * 32;
      float4 xv = *(const float4*)(xbase + (size_t)(r0 + row) * NIN);
      As[0][akq*4+0][row] = xv.x;
      As[0][akq*4+1][row] = xv.y;
      As[0][akq*4+2][row] = xv.z;
      As[0][akq*4+3][row] = xv.w;
      float4 wv = *(const float4*)(wbase + (size_t)row * NIN);
      Bs[0][akq*4+0][row] = wv.x;
      Bs[0][akq*4+1][row] = wv.y;
      Bs[0][akq*4+2][row] = wv.z;
      Bs[0][akq*4+3][row] = wv.w;
    }
  }
  __syncthreads();

  for (int c = 0; c < ccnt; ++c) {
    const int cur = c & 1;
    float4 xa[2], wb[2];
    const bool more = (c + 1 < ccnt);
    if (more) {
#pragma unroll
      for (int i = 0; i < 2; ++i) {
        int row = arow + i * 32;
        xa[i] = *(const float4*)(xbase + (size_t)(r0 + row) * NIN + (c + 1) * 16);
        wb[i] = *(const float4*)(wbase + (size_t)row * NIN + (c + 1) * 16);
      }
    }
#pragma unroll 4
    for (int k = 0; k < 16; ++k) {
      float4 a0 = *(const float4*)&As[cur][k][tm * 8];
      float4 a1 = *(const float4*)&As[cur][k][tm * 8 + 4];
      float4 b  = *(const float4*)&Bs[cur][k][tn * 4];
      FMA4(acc[0], a0.x, b);
      FMA4(acc[1], a0.y, b);
      FMA4(acc[2], a0.z, b);
      FMA4(acc[3], a0.w, b);
      FMA4(acc[4], a1.x, b);
      FMA4(acc[5], a1.y, b);
      FMA4(acc[6], a1.z, b);
      FMA4(acc[7], a1.w, b);
    }
    if (more) {
      const int nxt = cur ^ 1;
#pragma unroll
      for (int i = 0; i < 2; ++i) {
        int row = arow + i * 32;
        As[nxt][akq*4+0][row] = xa[i].x;
        As[nxt][akq*4+1][row] = xa[i].y;
        As[nxt][akq*4+2][row] = xa[i].z;
        As[nxt][akq*4+3][row] = xa[i].w;
        Bs[nxt][akq*4+0][row] = wb[i].x;
        Bs[nxt][akq*4+1][row] = wb[i].y;
        Bs[nxt][akq*4+2][row] = wb[i].z;
        Bs[nxt][akq*4+3][row] = wb[i].w;
      }
    }
    __syncthreads();
  }

  // epilogue: b-major write (whole tile shares one t since 64 | 256)
  const int t0  = r0 >> 8;
  const int bb0 = r0 & 255;
  float* op = P + (size_t)s * PLANE;
#pragma unroll
  for (int i = 0; i < 8; ++i) {
    const int bb = bb0 + tm * 8 + i;
    *(float4*)(op + ((size_t)bb * T_STEPS + t0) * 64 + tn * 4) = acc[i];
  }
}

// ---------------------------------------------------------------------------
// Kernel 2: I0T[fi] = sum_s P[s][fi] + b0  (all b-major; fully coalesced).
// 1600 blocks x 256 threads, one float4 per thread.
// ---------------------------------------------------------------------------
__global__ __launch_bounds__(256) void reduce_kernel(
    const float* __restrict__ P, const float* __restrict__ b0,
    float* __restrict__ I0T) {
  const int fi = blockIdx.x * 256 + threadIdx.x;   // f4 index 0..409599
  const int q  = fi & 15;

  const float4* p = (const float4*)P;
  const size_t pstep = PLANE / 4;
  float4 v  = p[fi];
  float4 u1 = p[fi + pstep];
  float4 u2 = p[fi + 2 * pstep];
  float4 u3 = p[fi + 3 * pstep];
  v.x += u1.x; v.y += u1.y; v.z += u1.z; v.w += u1.w;
  v.x += u2.x; v.y += u2.y; v.z += u2.z; v.w += u2.w;
  v.x += u3.x; v.y += u3.y; v.z += u3.z; v.w += u3.w;
  float4 bv = ((const float4*)b0)[q];
  v.x += bv.x; v.y += bv.y; v.z += bv.z; v.w += bv.w;
  ((float4*)I0T)[fi] = v;
}

// ---------------------------------------------------------------------------
// Kernel 3: one block per batch element (R9's lean fused body, measured).
// ---------------------------------------------------------------------------
__global__ __launch_bounds__(256) void fused_kernel(
    const float* __restrict__ I0T,
    const float* __restrict__ W1, const float* __restrict__ b1,
    const float* __restrict__ W2, const float* __restrict__ b2,
    float* __restrict__ out) {
  __shared__ float bufA[112][68];
  __shared__ float sW1t[64][68];
  __shared__ float sW2[N2][68];
  __shared__ float sI2[T_STEPS][N2];

  const int b   = blockIdx.x;
  const int tid = threadIdx.x;
  const int j   = tid & 63;
  const int tq  = tid >> 6;
  float* outSpk = out;
  float* laySpk = out + T_STEPS * BATCH * N2;

  {
    const float4* src = (const float4*)I0T + (size_t)b * (T_STEPS * 16);
    for (int idx = tid; idx < T_STEPS * 16; idx += 256) {
      float4 v = src[idx];
      int t = idx >> 4, j4 = idx & 15;
      *(float4*)&bufA[t][j4 * 4] = v;
    }
  }
  __syncthreads();

  if (tq == 0) {
    float v = 0.0f;
#pragma unroll
    for (int g = 0; g < 4; ++g) {
      float ic[25];
#pragma unroll
      for (int i = 0; i < 25; ++i) ic[i] = bufA[g * 25 + i][j];
#pragma unroll
      for (int i = 0; i < 25; ++i) {
        v = v + 0.05f * ((0.0f - v) + ic[i]);
        float z = (v > 1.0f) ? 1.0f : 0.0f;
        v -= z;
        ic[i] = z;
      }
#pragma unroll
      for (int i = 0; i < 25; ++i) bufA[g * 25 + i][j] = ic[i];
    }
  } else {
    for (int idx = tid - 64; idx < 64 * 16; idx += 192) {
      int i = idx >> 4, jv = idx & 15;
      float4 wv = *(const float4*)(W1 + (size_t)i * 64 + jv * 4);
      sW1t[jv * 4 + 0][i] = wv.x;
      sW1t[jv * 4 + 1][i] = wv.y;
      sW1t[jv * 4 + 2][i] = wv.z;
      sW1t[jv * 4 + 3][i] = wv.w;
    }
    for (int idx = tid - 64; idx < N2 * 16; idx += 192) {
      int o = idx >> 4, jv = idx & 15;
      *(float4*)&sW2[o][jv * 4] = *(const float4*)(W2 + (size_t)o * 64 + jv * 4);
    }
  }
  __syncthreads();

  for (int idx = tid; idx < T_STEPS * 16; idx += 256) {
    int t = idx >> 4, jv = idx & 15;
    *(float4*)(laySpk + (size_t)t * CHUNK + b * 64 + jv * 4) =
        *(const float4*)&bufA[t][jv * 4];
  }

  const int iq = tid & 15;
  const int ts = tid >> 4;
  float g1[4][7];
  {
    float4 bias = *(const float4*)(b1 + iq * 4);
#pragma unroll
    for (int tt = 0; tt < 7; ++tt) {
      g1[0][tt] = bias.x; g1[1][tt] = bias.y; g1[2][tt] = bias.z; g1[3][tt] = bias.w;
    }
#pragma unroll
    for (int jq = 0; jq < 16; ++jq) {
      float4 zv4[7];
#pragma unroll
      for (int tt = 0; tt < 7; ++tt)
        zv4[tt] = *(const float4*)&bufA[ts * 7 + tt][jq * 4];
      float4 w4[4];
#pragma unroll
      for (int e = 0; e < 4; ++e)
        w4[e] = *(const float4*)&sW1t[jq * 4 + e][iq * 4];
#pragma unroll
      for (int e = 0; e < 4; ++e) {
#pragma unroll
        for (int tt = 0; tt < 7; ++tt) {
          float zv = ((const float*)&zv4[tt])[e];
          g1[0][tt] = fmaf(zv, w4[e].x, g1[0][tt]);
          g1[1][tt] = fmaf(zv, w4[e].y, g1[1][tt]);
          g1[2][tt] = fmaf(zv, w4[e].z, g1[2][tt]);
          g1[3][tt] = fmaf(zv, w4[e].w, g1[3][tt]);
        }
      }
    }
  }
  __syncthreads();
#pragma unroll
  for (int tt = 0; tt < 7; ++tt) {
    float4 o = {g1[0][tt], g1[1][tt], g1[2][tt], g1[3][tt]};
    *(float4*)&bufA[ts * 7 + tt][iq * 4] = o;
  }
  __syncthreads();

  if (tq == 0) {
    float v = 0.0f;
#pragma unroll
    for (int g = 0; g < 4; ++g) {
      float ic[25];
#pragma unroll
      for (int i = 0; i < 25; ++i) ic[i] = bufA[g * 25 + i][j];
#pragma unroll
      for (int i = 0; i < 25; ++i) {
        v = v + 0.05f * ((0.0f - v) + ic[i]);
        float z = (v > 1.0f) ? 1.0f : 0.0f;
        v -= z;
        ic[i] = z;
      }
#pragma unroll
      for (int i = 0; i < 25; ++i) bufA[g * 25 + i][j] = ic[i];
    }
  }
  __syncthreads();

  for (int idx = tid; idx < T_STEPS * 16; idx += 256) {
    int t = idx >> 4, jv = idx & 15;
    *(float4*)(laySpk + (size_t)t * CHUNK + BATCH * N0 + b * 64 + jv * 4) =
        *(const float4*)&bufA[t][jv * 4];
  }

  for (int idx = tid; idx < T_STEPS * N2; idx += 256) {
    int t = idx / N2, o = idx % N2;
    float a = b2[o];
#pragma unroll
    for (int jq = 0; jq < 16; ++jq) {
      float4 z = *(const float4*)&bufA[t][jq * 4];
      float4 wv = *(const float4*)&sW2[o][jq * 4];
      a += z.x * wv.x;
      a += z.y * wv.y;
      a += z.z * wv.z;
      a += z.w * wv.w;
    }
    sI2[t][o] = a;
  }
  __syncthreads();

  if (tid < N2) {
    float v = 0.0f;
#pragma unroll
    for (int g = 0; g < 4; ++g) {
      float ic[25];
#pragma unroll
      for (int i = 0; i < 25; ++i) ic[i] = sI2[g * 25 + i][tid];
#pragma unroll
      for (int i = 0; i < 25; ++i) {
        v = v + 0.05f * ((0.0f - v) + ic[i]);
        float z = (v > 1.0f) ? 1.0f : 0.0f;
        v -= z;
        ic[i] = z;
      }
#pragma unroll
      for (int i = 0; i < 25; ++i) sI2[g * 25 + i][tid] = ic[i];
    }
  }
  __syncthreads();

  for (int idx = tid; idx < T_STEPS * N2; idx += 256) {
    int t = idx / N2, o = idx % N2;
    float z = sI2[t][o];
    outSpk[(size_t)t * (BATCH * N2) + b * N2 + o] = z;
    laySpk[(size_t)t * CHUNK + BATCH * (N0 + N1) + b * N2 + o] = z;
  }
}

extern "C" void kernel_launch(void* const* d_in, const int* in_sizes, int n_in,
                              void* d_out, int out_size, void* d_ws, size_t ws_size,
                              hipStream_t stream) {
  const float* inp = (const float*)d_in[0];
  const float* W0  = (const float*)d_in[1];
  const float* b0  = (const float*)d_in[2];
  const float* W1  = (const float*)d_in[3];
  const float* b1  = (const float*)d_in[4];
  const float* W2  = (const float*)d_in[5];
  const float* b2  = (const float*)d_in[6];

  float* P   = (float*)d_ws;                      // 4 planes, b-major
  float* I0T = P + (size_t)NSPLIT * PLANE;        // 6.55 MB, b-major

  gemm0_kernel<<<dim3(25600 / BM, NSPLIT), dim3(128), 0, stream>>>(inp, W0, P);
  reduce_kernel<<<dim3(1600), dim3(256), 0, stream>>>(P, b0, I0T);
  fused_kernel<<<dim3(BATCH), dim3(256), 0, stream>>>(I0T, W1, b1, W2, b2,
                                                      (float*)d_out);
}

// Round 17
// 69.062 us; speedup vs baseline: 1.0930x; 1.0397x over previous
//
#include <hip/hip_runtime.h>

#define T_STEPS 100
#define BATCH 256
#define NIN 784
#define N0 64
#define N1 64
#define N2 10
#define CHUNK (BATCH*N0 + BATCH*N1 + BATCH*N2)   // 35328
#define NCHUNKS 49                               // 784 / 16
#define BM 32                                    // gemm0 tile rows

#define FMA4(d, s, v) \
  d.x = fmaf((s), (v).x, d.x); d.y = fmaf((s), (v).y, d.y); \
  d.z = fmaf((s), (v).z, d.z); d.w = fmaf((s), (v).w, d.w);

// ---------------------------------------------------------------------------
// Kernel 1: I0T = X @ W0^T + b0, f32, in-block split-K.
// Block = 32 rows x 64 cols, 4 waves = k-chunk split {13,12,12,12}
// (identical chunk boundaries / FMA order to R16's gemm0, which passed).
// Each wave stages its 16-k chunk into WAVE-PRIVATE LDS (A 32x16, B 64x16);
// same-wave DS ops are in-order -> NO barriers in the k-loop. Global loads
// for chunk c+1 are issued into registers before chunk c's compute.
// Epilogue: one barrier, LDS reduce of the 4 wave-partials (s ascending,
// bias last — exactly R16's reduce order), b-major write of final I0T.
// Grid 800 x 256 thr = 3200 waves; LDS 34.8 KB (staging aliased by red).
// ---------------------------------------------------------------------------
__global__ __launch_bounds__(256, 4) void gemm0_kernel(
    const float* __restrict__ X, const float* __restrict__ W0,
    const float* __restrict__ b0, float* __restrict__ I0T) {
  __shared__ __align__(16) char smem[4 * 32 * 68 * 4];   // 34816 B

  const int tid = threadIdx.x;
  const int r0  = blockIdx.x * BM;
  const int wid = tid >> 6;                      // wave = k-split s
  const int l   = tid & 63;
  const int tn  = l & 15;                        // cols tn*4..+3
  const int tm  = l >> 4;                        // row-group 0..3: rows tm*8..+7

  float* smf = (float*)smem;
  float* Aw  = smf + wid * (16 * 36);            // wave-private A [16][36]
  float* Bw  = smf + 4 * 16 * 36 + wid * (16 * 68);  // wave-private B [16][68]
  float (*red)[32][68] = (float(*)[32][68])smf;  // aliases staging (after sync)

  const int per  = NCHUNKS / 4;                  // 12
  const int rem  = NCHUNKS % 4;                  // 1
  const int cbeg = wid * per + (wid < rem ? wid : rem);
  const int ccnt = per + (wid < rem ? 1 : 0);    // {13,12,12,12}

  float4 acc[8];
#pragma unroll
  for (int i = 0; i < 8; ++i) acc[i] = float4{0.f, 0.f, 0.f, 0.f};

  // staging maps (per wave): A: row = l&31, k-half = l>>5 (2 f4 = 8 k)
  //                          B: col = l, 4 f4 = 16 k
  const int arow = l & 31;
  const int ah   = l >> 5;
  const float* xrow = X  + (size_t)(r0 + arow) * NIN;
  const float* wrow = W0 + (size_t)l * NIN;

  // ---- prologue: stage chunk cbeg
  {
    const int kb = cbeg * 16;
    float4 xa0 = *(const float4*)(xrow + kb + ah * 8);
    float4 xa1 = *(const float4*)(xrow + kb + ah * 8 + 4);
#pragma unroll
    for (int e = 0; e < 4; ++e) {
      Aw[(ah * 8 + e)     * 36 + arow] = ((const float*)&xa0)[e];
      Aw[(ah * 8 + 4 + e) * 36 + arow] = ((const float*)&xa1)[e];
    }
#pragma unroll
    for (int f = 0; f < 4; ++f) {
      float4 wv = *(const float4*)(wrow + kb + f * 4);
#pragma unroll
      for (int e = 0; e < 4; ++e) Bw[(f * 4 + e) * 68 + l] = ((const float*)&wv)[e];
    }
  }

  for (int c = 0; c < ccnt; ++c) {
    const bool more = (c + 1 < ccnt);
    // ---- issue next chunk's global loads into registers
    float4 nxa0, nxa1, nwb[4];
    if (more) {
      const int kb = (cbeg + c + 1) * 16;
      nxa0 = *(const float4*)(xrow + kb + ah * 8);
      nxa1 = *(const float4*)(xrow + kb + ah * 8 + 4);
#pragma unroll
      for (int f = 0; f < 4; ++f)
        nwb[f] = *(const float4*)(wrow + kb + f * 4);
    }

    // ---- compute chunk c from wave-private LDS (no barrier needed)
#pragma unroll 4
    for (int k = 0; k < 16; ++k) {
      float4 a0 = *(const float4*)(Aw + k * 36 + tm * 8);
      float4 a1 = *(const float4*)(Aw + k * 36 + tm * 8 + 4);
      float4 b  = *(const float4*)(Bw + k * 68 + tn * 4);
      FMA4(acc[0], a0.x, b);
      FMA4(acc[1], a0.y, b);
      FMA4(acc[2], a0.z, b);
      FMA4(acc[3], a0.w, b);
      FMA4(acc[4], a1.x, b);
      FMA4(acc[5], a1.y, b);
      FMA4(acc[6], a1.z, b);
      FMA4(acc[7], a1.w, b);
    }

    // ---- overwrite staging with chunk c+1 (in-order DS: after reads above)
    if (more) {
#pragma unroll
      for (int e = 0; e < 4; ++e) {
        Aw[(ah * 8 + e)     * 36 + arow] = ((const float*)&nxa0)[e];
        Aw[(ah * 8 + 4 + e) * 36 + arow] = ((const float*)&nxa1)[e];
      }
#pragma unroll
      for (int f = 0; f < 4; ++f)
#pragma unroll
        for (int e = 0; e < 4; ++e)
          Bw[(f * 4 + e) * 68 + l] = ((const float*)&nwb[f])[e];
    }
  }

  // ---- all waves done with staging before red overlays it
  __syncthreads();
#pragma unroll
  for (int i = 0; i < 8; ++i)
    *(float4*)&red[wid][tm * 8 + i][tn * 4] = acc[i];
  __syncthreads();

  // ---- reduce 4 wave-partials (s ascending) + bias, write b-major I0T
  {
    const int t0  = r0 >> 8;
    const int bb0 = r0 & 255;
    int row = tid >> 4, q = tid & 15;            // wait: need 32 rows x 16 q = 512 slots, have 256 threads
    for (int idx = tid; idx < 32 * 16; idx += 256) {
      row = idx >> 4; q = idx & 15;
      float4 v  = *(const float4*)&red[0][row][q * 4];
      float4 u1 = *(const float4*)&red[1][row][q * 4];
      float4 u2 = *(const float4*)&red[2][row][q * 4];
      float4 u3 = *(const float4*)&red[3][row][q * 4];
      v.x += u1.x; v.y += u1.y; v.z += u1.z; v.w += u1.w;
      v.x += u2.x; v.y += u2.y; v.z += u2.z; v.w += u2.w;
      v.x += u3.x; v.y += u3.y; v.z += u3.z; v.w += u3.w;
      float4 bv = ((const float4*)b0)[q];
      v.x += bv.x; v.y += bv.y; v.z += bv.z; v.w += bv.w;
      ((float4*)I0T)[((size_t)(bb0 + row) * T_STEPS + t0) * 16 + q] = v;
    }
  }
}

// ---------------------------------------------------------------------------
// Kernel 2: one block per batch element (R9's lean fused body, measured).
// ---------------------------------------------------------------------------
__global__ __launch_bounds__(256) void fused_kernel(
    const float* __restrict__ I0T,
    const float* __restrict__ W1, const float* __restrict__ b1,
    const float* __restrict__ W2, const float* __restrict__ b2,
    float* __restrict__ out) {
  __shared__ float bufA[112][68];
  __shared__ float sW1t[64][68];
  __shared__ float sW2[N2][68];
  __shared__ float sI2[T_STEPS][N2];

  const int b   = blockIdx.x;
  const int tid = threadIdx.x;
  const int j   = tid & 63;
  const int tq  = tid >> 6;
  float* outSpk = out;
  float* laySpk = out + T_STEPS * BATCH * N2;

  {
    const float4* src = (const float4*)I0T + (size_t)b * (T_STEPS * 16);
    for (int idx = tid; idx < T_STEPS * 16; idx += 256) {
      float4 v = src[idx];
      int t = idx >> 4, j4 = idx & 15;
      *(float4*)&bufA[t][j4 * 4] = v;
    }
  }
  __syncthreads();

  if (tq == 0) {
    float v = 0.0f;
#pragma unroll
    for (int g = 0; g < 4; ++g) {
      float ic[25];
#pragma unroll
      for (int i = 0; i < 25; ++i) ic[i] = bufA[g * 25 + i][j];
#pragma unroll
      for (int i = 0; i < 25; ++i) {
        v = v + 0.05f * ((0.0f - v) + ic[i]);
        float z = (v > 1.0f) ? 1.0f : 0.0f;
        v -= z;
        ic[i] = z;
      }
#pragma unroll
      for (int i = 0; i < 25; ++i) bufA[g * 25 + i][j] = ic[i];
    }
  } else {
    for (int idx = tid - 64; idx < 64 * 16; idx += 192) {
      int i = idx >> 4, jv = idx & 15;
      float4 wv = *(const float4*)(W1 + (size_t)i * 64 + jv * 4);
      sW1t[jv * 4 + 0][i] = wv.x;
      sW1t[jv * 4 + 1][i] = wv.y;
      sW1t[jv * 4 + 2][i] = wv.z;
      sW1t[jv * 4 + 3][i] = wv.w;
    }
    for (int idx = tid - 64; idx < N2 * 16; idx += 192) {
      int o = idx >> 4, jv = idx & 15;
      *(float4*)&sW2[o][jv * 4] = *(const float4*)(W2 + (size_t)o * 64 + jv * 4);
    }
  }
  __syncthreads();

  for (int idx = tid; idx < T_STEPS * 16; idx += 256) {
    int t = idx >> 4, jv = idx & 15;
    *(float4*)(laySpk + (size_t)t * CHUNK + b * 64 + jv * 4) =
        *(const float4*)&bufA[t][jv * 4];
  }

  const int iq = tid & 15;
  const int ts = tid >> 4;
  float g1[4][7];
  {
    float4 bias = *(const float4*)(b1 + iq * 4);
#pragma unroll
    for (int tt = 0; tt < 7; ++tt) {
      g1[0][tt] = bias.x; g1[1][tt] = bias.y; g1[2][tt] = bias.z; g1[3][tt] = bias.w;
    }
#pragma unroll
    for (int jq = 0; jq < 16; ++jq) {
      float4 zv4[7];
#pragma unroll
      for (int tt = 0; tt < 7; ++tt)
        zv4[tt] = *(const float4*)&bufA[ts * 7 + tt][jq * 4];
      float4 w4[4];
#pragma unroll
      for (int e = 0; e < 4; ++e)
        w4[e] = *(const float4*)&sW1t[jq * 4 + e][iq * 4];
#pragma unroll
      for (int e = 0; e < 4; ++e) {
#pragma unroll
        for (int tt = 0; tt < 7; ++tt) {
          float zv = ((const float*)&zv4[tt])[e];
          g1[0][tt] = fmaf(zv, w4[e].x, g1[0][tt]);
          g1[1][tt] = fmaf(zv, w4[e].y, g1[1][tt]);
          g1[2][tt] = fmaf(zv, w4[e].z, g1[2][tt]);
          g1[3][tt] = fmaf(zv, w4[e].w, g1[3][tt]);
        }
      }
    }
  }
  __syncthreads();
#pragma unroll
  for (int tt = 0; tt < 7; ++tt) {
    float4 o = {g1[0][tt], g1[1][tt], g1[2][tt], g1[3][tt]};
    *(float4*)&bufA[ts * 7 + tt][iq * 4] = o;
  }
  __syncthreads();

  if (tq == 0) {
    float v = 0.0f;
#pragma unroll
    for (int g = 0; g < 4; ++g) {
      float ic[25];
#pragma unroll
      for (int i = 0; i < 25; ++i) ic[i] = bufA[g * 25 + i][j];
#pragma unroll
      for (int i = 0; i < 25; ++i) {
        v = v + 0.05f * ((0.0f - v) + ic[i]);
        float z = (v > 1.0f) ? 1.0f : 0.0f;
        v -= z;
        ic[i] = z;
      }
#pragma unroll
      for (int i = 0; i < 25; ++i) bufA[g * 25 + i][j] = ic[i];
    }
  }
  __syncthreads();

  for (int idx = tid; idx < T_STEPS * 16; idx += 256) {
    int t = idx >> 4, jv = idx & 15;
    *(float4*)(laySpk + (size_t)t * CHUNK + BATCH * N0 + b * 64 + jv * 4) =
        *(const float4*)&bufA[t][jv * 4];
  }

  for (int idx = tid; idx < T_STEPS * N2; idx += 256) {
    int t = idx / N2, o = idx % N2;
    float a = b2[o];
#pragma unroll
    for (int jq = 0; jq < 16; ++jq) {
      float4 z = *(const float4*)&bufA[t][jq * 4];
      float4 wv = *(const float4*)&sW2[o][jq * 4];
      a += z.x * wv.x;
      a += z.y * wv.y;
      a += z.z * wv.z;
      a += z.w * wv.w;
    }
    sI2[t][o] = a;
  }
  __syncthreads();

  if (tid < N2) {
    float v = 0.0f;
#pragma unroll
    for (int g = 0; g < 4; ++g) {
      float ic[25];
#pragma unroll
      for (int i = 0; i < 25; ++i) ic[i] = sI2[g * 25 + i][tid];
#pragma unroll
      for (int i = 0; i < 25; ++i) {
        v = v + 0.05f * ((0.0f - v) + ic[i]);
        float z = (v > 1.0f) ? 1.0f : 0.0f;
        v -= z;
        ic[i] = z;
      }
#pragma unroll
      for (int i = 0; i < 25; ++i) sI2[g * 25 + i][tid] = ic[i];
    }
  }
  __syncthreads();

  for (int idx = tid; idx < T_STEPS * N2; idx += 256) {
    int t = idx / N2, o = idx % N2;
    float z = sI2[t][o];
    outSpk[(size_t)t * (BATCH * N2) + b * N2 + o] = z;
    laySpk[(size_t)t * CHUNK + BATCH * (N0 + N1) + b * N2 + o] = z;
  }
}

extern "C" void kernel_launch(void* const* d_in, const int* in_sizes, int n_in,
                              void* d_out, int out_size, void* d_ws, size_t ws_size,
                              hipStream_t stream) {
  const float* inp = (const float*)d_in[0];
  const float* W0  = (const float*)d_in[1];
  const float* b0  = (const float*)d_in[2];
  const float* W1  = (const float*)d_in[3];
  const float* b1  = (const float*)d_in[4];
  const float* W2  = (const float*)d_in[5];
  const float* b2  = (const float*)d_in[6];

  float* I0T = (float*)d_ws;   // 6.55 MB, b-major [b][t][j]

  gemm0_kernel<<<dim3(25600 / BM), dim3(256), 0, stream>>>(inp, W0, b0, I0T);
  fused_kernel<<<dim3(BATCH), dim3(256), 0, stream>>>(I0T, W1, b1, W2, b2,
                                                      (float*)d_out);
}

// Round 18
// 68.103 us; speedup vs baseline: 1.1084x; 1.0141x over previous
//
#include <hip/hip_runtime.h>

#define T_STEPS 100
#define BATCH 256
#define NIN 784
#define N0 64
#define N1 64
#define N2 10
#define CHUNK (BATCH*N0 + BATCH*N1 + BATCH*N2)   // 35328
#define NCHUNKS 49                               // 784 / 16
#define NSPLIT 4
#define PLANE (BATCH*T_STEPS*64)                 // partial plane (floats), b-major
#define BM 64                                    // gemm0 tile rows

#define FMA4(d, s, v) \
  d.x = fmaf((s), (v).x, d.x); d.y = fmaf((s), (v).y, d.y); \
  d.z = fmaf((s), (v).z, d.z); d.w = fmaf((s), (v).w, d.w);

#define ADD4(d, u) \
  d.x += (u).x; d.y += (u).y; d.z += (u).z; d.w += (u).w;

// ---------------------------------------------------------------------------
// Kernel 1: partial I0 = X @ W0^T. Tile 64x64, 128 threads, micro-tile 8x4,
// double-buffered LDS, 1 sync/chunk, K-split {13,12,12,12} over blockIdx.y.
// Output b-major P[s][b][t][j]. (R16's gemm0 verbatim — measured 46.7 us.)
// ---------------------------------------------------------------------------
__global__ __launch_bounds__(128, 4) void gemm0_kernel(
    const float* __restrict__ X, const float* __restrict__ W0,
    float* __restrict__ P) {
  __shared__ float As[2][16][68];   // [buf][k][row]
  __shared__ float Bs[2][16][68];   // [buf][k][col]

  const int tid = threadIdx.x;
  const int r0  = blockIdx.x * BM;
  const int s   = blockIdx.y;
  const int tn  = tid & 15;          // cols tn*4..+3
  const int tm  = tid >> 4;          // row-group 0..7: rows tm*8..+7

  const int per  = NCHUNKS / NSPLIT;      // 12
  const int rem  = NCHUNKS % NSPLIT;      // 1
  const int cbeg = s * per + (s < rem ? s : rem);
  const int ccnt = per + (s < rem ? 1 : 0);

  float4 acc[8];
#pragma unroll
  for (int i = 0; i < 8; ++i) acc[i] = float4{0.f, 0.f, 0.f, 0.f};

  const int arow = tid >> 2;         // 0..31 (+32 for second)
  const int akq  = tid & 3;          // k-quad

  const float* xbase = X  + (size_t)cbeg * 16 + akq * 4;
  const float* wbase = W0 + (size_t)cbeg * 16 + akq * 4;

  // prologue: chunk 0 -> buffer 0
  {
#pragma unroll
    for (int i = 0; i < 2; ++i) {
      int row = arow + i * 32;
      float4 xv = *(const float4*)(xbase + (size_t)(r0 + row) * NIN);
      As[0][akq*4+0][row] = xv.x;
      As[0][akq*4+1][row] = xv.y;
      As[0][akq*4+2][row] = xv.z;
      As[0][akq*4+3][row] = xv.w;
      float4 wv = *(const float4*)(wbase + (size_t)row * NIN);
      Bs[0][akq*4+0][row] = wv.x;
      Bs[0][akq*4+1][row] = wv.y;
      Bs[0][akq*4+2][row] = wv.z;
      Bs[0][akq*4+3][row] = wv.w;
    }
  }
  __syncthreads();

  for (int c = 0; c < ccnt; ++c) {
    const int cur = c & 1;
    float4 xa[2], wb[2];
    const bool more = (c + 1 < ccnt);
    if (more) {
#pragma unroll
      for (int i = 0; i < 2; ++i) {
        int row = arow + i * 32;
        xa[i] = *(const float4*)(xbase + (size_t)(r0 + row) * NIN + (c + 1) * 16);
        wb[i] = *(const float4*)(wbase + (size_t)row * NIN + (c + 1) * 16);
      }
    }
#pragma unroll 4
    for (int k = 0; k < 16; ++k) {
      float4 a0 = *(const float4*)&As[cur][k][tm * 8];
      float4 a1 = *(const float4*)&As[cur][k][tm * 8 + 4];
      float4 b  = *(const float4*)&Bs[cur][k][tn * 4];
      FMA4(acc[0], a0.x, b);
      FMA4(acc[1], a0.y, b);
      FMA4(acc[2], a0.z, b);
      FMA4(acc[3], a0.w, b);
      FMA4(acc[4], a1.x, b);
      FMA4(acc[5], a1.y, b);
      FMA4(acc[6], a1.z, b);
      FMA4(acc[7], a1.w, b);
    }
    if (more) {
      const int nxt = cur ^ 1;
#pragma unroll
      for (int i = 0; i < 2; ++i) {
        int row = arow + i * 32;
        As[nxt][akq*4+0][row] = xa[i].x;
        As[nxt][akq*4+1][row] = xa[i].y;
        As[nxt][akq*4+2][row] = xa[i].z;
        As[nxt][akq*4+3][row] = xa[i].w;
        Bs[nxt][akq*4+0][row] = wb[i].x;
        Bs[nxt][akq*4+1][row] = wb[i].y;
        Bs[nxt][akq*4+2][row] = wb[i].z;
        Bs[nxt][akq*4+3][row] = wb[i].w;
      }
    }
    __syncthreads();
  }

  // epilogue: b-major write (whole tile shares one t since 64 | 256)
  const int t0  = r0 >> 8;
  const int bb0 = r0 & 255;
  float* op = P + (size_t)s * PLANE;
#pragma unroll
  for (int i = 0; i < 8; ++i) {
    const int bb = bb0 + tm * 8 + i;
    *(float4*)(op + ((size_t)bb * T_STEPS + t0) * 64 + tn * 4) = acc[i];
  }
}

// ---------------------------------------------------------------------------
// Kernel 2: one block per batch element. Staging sums the 4 b-major plane
// slabs + bias with HAND-UNROLLED wide-issue loads (6 strips + 1 guarded,
// all loads issued before any sums -> 24-28 loads in flight). Sum order
// identical to R16's reduce kernel (bit-identical output). Then the proven
// R9 fused body: scan0 -> GEMM1 -> scan1 -> GEMM2 -> scan2.
// ---------------------------------------------------------------------------
__global__ __launch_bounds__(256) void fused_kernel(
    const float* __restrict__ P, const float* __restrict__ b0,
    const float* __restrict__ W1, const float* __restrict__ b1,
    const float* __restrict__ W2, const float* __restrict__ b2,
    float* __restrict__ out) {
  __shared__ float bufA[112][68];
  __shared__ float sW1t[64][68];
  __shared__ float sW2[N2][68];
  __shared__ float sI2[T_STEPS][N2];

  const int b   = blockIdx.x;
  const int tid = threadIdx.x;
  const int j   = tid & 63;
  const int tq  = tid >> 6;
  float* outSpk = out;
  float* laySpk = out + T_STEPS * BATCH * N2;

  // ---- stage I0 = ((P0+P1)+P2)+P3 + b0  (wide-issue, R16 reduce order)
  {
    const float4* base = (const float4*)P + (size_t)b * (T_STEPS * 16);
    const size_t ps = PLANE / 4;
    float4 v[7], u1[7], u2[7], u3[7];
#pragma unroll
    for (int i = 0; i < 6; ++i) {               // issue 24 loads back-to-back
      int idx = tid + 256 * i;
      v[i]  = base[idx];
      u1[i] = base[idx + ps];
      u2[i] = base[idx + 2 * ps];
      u3[i] = base[idx + 3 * ps];
    }
    const bool last = (tid < 64);               // idx6 = tid+1536 < 1600
    if (last) {
      int idx = tid + 1536;
      v[6]  = base[idx];
      u1[6] = base[idx + ps];
      u2[6] = base[idx + 2 * ps];
      u3[6] = base[idx + 3 * ps];
    }
#pragma unroll
    for (int i = 0; i < 6; ++i) {
      int idx = tid + 256 * i;
      int t = idx >> 4, q = idx & 15;
      float4 r = v[i];
      ADD4(r, u1[i]);
      ADD4(r, u2[i]);
      ADD4(r, u3[i]);
      float4 bv = ((const float4*)b0)[q];
      ADD4(r, bv);
      *(float4*)&bufA[t][q * 4] = r;
    }
    if (last) {
      int idx = tid + 1536;
      int t = idx >> 4, q = idx & 15;
      float4 r = v[6];
      ADD4(r, u1[6]);
      ADD4(r, u2[6]);
      ADD4(r, u3[6]);
      float4 bv = ((const float4*)b0)[q];
      ADD4(r, bv);
      *(float4*)&bufA[t][q * 4] = r;
    }
  }
  __syncthreads();

  // ---- scan0 (wave 0, batched) || W1/W2 staging (waves 1-3)
  if (tq == 0) {
    float v = 0.0f;
#pragma unroll
    for (int g = 0; g < 4; ++g) {
      float ic[25];
#pragma unroll
      for (int i = 0; i < 25; ++i) ic[i] = bufA[g * 25 + i][j];
#pragma unroll
      for (int i = 0; i < 25; ++i) {
        v = v + 0.05f * ((0.0f - v) + ic[i]);
        float z = (v > 1.0f) ? 1.0f : 0.0f;
        v -= z;
        ic[i] = z;
      }
#pragma unroll
      for (int i = 0; i < 25; ++i) bufA[g * 25 + i][j] = ic[i];
    }
  } else {
    for (int idx = tid - 64; idx < 64 * 16; idx += 192) {
      int i = idx >> 4, jv = idx & 15;
      float4 wv = *(const float4*)(W1 + (size_t)i * 64 + jv * 4);
      sW1t[jv * 4 + 0][i] = wv.x;
      sW1t[jv * 4 + 1][i] = wv.y;
      sW1t[jv * 4 + 2][i] = wv.z;
      sW1t[jv * 4 + 3][i] = wv.w;
    }
    for (int idx = tid - 64; idx < N2 * 16; idx += 192) {
      int o = idx >> 4, jv = idx & 15;
      *(float4*)&sW2[o][jv * 4] = *(const float4*)(W2 + (size_t)o * 64 + jv * 4);
    }
  }
  __syncthreads();

  // ---- z0 -> layer_spikes
  for (int idx = tid; idx < T_STEPS * 16; idx += 256) {
    int t = idx >> 4, jv = idx & 15;
    *(float4*)(laySpk + (size_t)t * CHUNK + b * 64 + jv * 4) =
        *(const float4*)&bufA[t][jv * 4];
  }

  // ---- GEMM1
  const int iq = tid & 15;
  const int ts = tid >> 4;
  float g1[4][7];
  {
    float4 bias = *(const float4*)(b1 + iq * 4);
#pragma unroll
    for (int tt = 0; tt < 7; ++tt) {
      g1[0][tt] = bias.x; g1[1][tt] = bias.y; g1[2][tt] = bias.z; g1[3][tt] = bias.w;
    }
#pragma unroll
    for (int jq = 0; jq < 16; ++jq) {
      float4 zv4[7];
#pragma unroll
      for (int tt = 0; tt < 7; ++tt)
        zv4[tt] = *(const float4*)&bufA[ts * 7 + tt][jq * 4];
      float4 w4[4];
#pragma unroll
      for (int e = 0; e < 4; ++e)
        w4[e] = *(const float4*)&sW1t[jq * 4 + e][iq * 4];
#pragma unroll
      for (int e = 0; e < 4; ++e) {
#pragma unroll
        for (int tt = 0; tt < 7; ++tt) {
          float zv = ((const float*)&zv4[tt])[e];
          g1[0][tt] = fmaf(zv, w4[e].x, g1[0][tt]);
          g1[1][tt] = fmaf(zv, w4[e].y, g1[1][tt]);
          g1[2][tt] = fmaf(zv, w4[e].z, g1[2][tt]);
          g1[3][tt] = fmaf(zv, w4[e].w, g1[3][tt]);
        }
      }
    }
  }
  __syncthreads();
#pragma unroll
  for (int tt = 0; tt < 7; ++tt) {
    float4 o = {g1[0][tt], g1[1][tt], g1[2][tt], g1[3][tt]};
    *(float4*)&bufA[ts * 7 + tt][iq * 4] = o;
  }
  __syncthreads();

  // ---- scan1
  if (tq == 0) {
    float v = 0.0f;
#pragma unroll
    for (int g = 0; g < 4; ++g) {
      float ic[25];
#pragma unroll
      for (int i = 0; i < 25; ++i) ic[i] = bufA[g * 25 + i][j];
#pragma unroll
      for (int i = 0; i < 25; ++i) {
        v = v + 0.05f * ((0.0f - v) + ic[i]);
        float z = (v > 1.0f) ? 1.0f : 0.0f;
        v -= z;
        ic[i] = z;
      }
#pragma unroll
      for (int i = 0; i < 25; ++i) bufA[g * 25 + i][j] = ic[i];
    }
  }
  __syncthreads();

  // ---- z1 -> layer_spikes
  for (int idx = tid; idx < T_STEPS * 16; idx += 256) {
    int t = idx >> 4, jv = idx & 15;
    *(float4*)(laySpk + (size_t)t * CHUNK + BATCH * N0 + b * 64 + jv * 4) =
        *(const float4*)&bufA[t][jv * 4];
  }

  // ---- GEMM2
  for (int idx = tid; idx < T_STEPS * N2; idx += 256) {
    int t = idx / N2, o = idx % N2;
    float a = b2[o];
#pragma unroll
    for (int jq = 0; jq < 16; ++jq) {
      float4 z = *(const float4*)&bufA[t][jq * 4];
      float4 wv = *(const float4*)&sW2[o][jq * 4];
      a += z.x * wv.x;
      a += z.y * wv.y;
      a += z.z * wv.z;
      a += z.w * wv.w;
    }
    sI2[t][o] = a;
  }
  __syncthreads();

  // ---- scan2
  if (tid < N2) {
    float v = 0.0f;
#pragma unroll
    for (int g = 0; g < 4; ++g) {
      float ic[25];
#pragma unroll
      for (int i = 0; i < 25; ++i) ic[i] = sI2[g * 25 + i][tid];
#pragma unroll
      for (int i = 0; i < 25; ++i) {
        v = v + 0.05f * ((0.0f - v) + ic[i]);
        float z = (v > 1.0f) ? 1.0f : 0.0f;
        v -= z;
        ic[i] = z;
      }
#pragma unroll
      for (int i = 0; i < 25; ++i) sI2[g * 25 + i][tid] = ic[i];
    }
  }
  __syncthreads();

  for (int idx = tid; idx < T_STEPS * N2; idx += 256) {
    int t = idx / N2, o = idx % N2;
    float z = sI2[t][o];
    outSpk[(size_t)t * (BATCH * N2) + b * N2 + o] = z;
    laySpk[(size_t)t * CHUNK + BATCH * (N0 + N1) + b * N2 + o] = z;
  }
}

extern "C" void kernel_launch(void* const* d_in, const int* in_sizes, int n_in,
                              void* d_out, int out_size, void* d_ws, size_t ws_size,
                              hipStream_t stream) {
  const float* inp = (const float*)d_in[0];
  const float* W0  = (const float*)d_in[1];
  const float* b0  = (const float*)d_in[2];
  const float* W1  = (const float*)d_in[3];
  const float* b1  = (const float*)d_in[4];
  const float* W2  = (const float*)d_in[5];
  const float* b2  = (const float*)d_in[6];

  float* P = (float*)d_ws;   // 4 planes, b-major [s][b][t][j], 26.2 MB

  gemm0_kernel<<<dim3(25600 / BM, NSPLIT), dim3(128), 0, stream>>>(inp, W0, P);
  fused_kernel<<<dim3(BATCH), dim3(256), 0, stream>>>(P, b0, W1, b1, W2, b2,
                                                      (float*)d_out);
}

// Round 19
// 56.346 us; speedup vs baseline: 1.3397x; 1.2087x over previous
//
#include <hip/hip_runtime.h>

#define T_STEPS 100
#define BATCH 256
#define NIN 784
#define N0 64
#define N1 64
#define N2 10
#define CHUNK (BATCH*N0 + BATCH*N1 + BATCH*N2)   // 35328
#define I0ELEMS (25600*64)

typedef __attribute__((ext_vector_type(8))) short short8;
typedef __attribute__((ext_vector_type(4))) float f32x4;

__device__ inline short bf16_rne(float x) {
  unsigned u = __float_as_uint(x);
  unsigned h = (u + 0x7FFFu + ((u >> 16) & 1u)) >> 16;
  return (short)h;
}
__device__ inline float bf16_val(short h) {
  return __uint_as_float(((unsigned)(unsigned short)h) << 16);
}

// ---------------------------------------------------------------------------
// Kernel 0: pack W0 (f32 [64][784]) into bf16x3 fragment-coalesced layout
// W0p[c][p][ct][lane][e]: c = 32-k chunk (25, zero-pad k>=784), lane = MFMA
// B-frag lane (col = ct*16 + (l&15), k = c*32 + (l>>4)*8 + e). (R12, passed.)
// ---------------------------------------------------------------------------
__global__ __launch_bounds__(256) void prep_w0_pack(
    const float* __restrict__ W0, short* __restrict__ W0p) {
  int idx = blockIdx.x * 256 + threadIdx.x;      // 0..153599
  int e  = idx & 7;
  int r1 = idx >> 3;
  int l  = r1 & 63;
  int r2 = r1 >> 6;
  int ct = r2 & 3;
  int r3 = r2 >> 2;
  int p  = r3 % 3;
  int c  = r3 / 3;                               // 0..24
  int k   = c * 32 + (l >> 4) * 8 + e;
  int col = ct * 16 + (l & 15);
  float w = (k < NIN) ? W0[col * NIN + k] : 0.0f;
  short h0 = bf16_rne(w);
  float rr1 = w - bf16_val(h0);
  short h1 = bf16_rne(rr1);
  float rr2 = rr1 - bf16_val(h1);
  short h2 = bf16_rne(rr2);
  W0p[idx] = (p == 0) ? h0 : (p == 1) ? h1 : h2;
}

// ---------------------------------------------------------------------------
// Kernel 1: I0T = X @ W0^T + b0 via bf16x3 MFMA — R10's pipeline verbatim,
// with B swapped to the packed fragment-coalesced W0p (12 x 1KB coalesced
// loads per chunk instead of ~130-line gathers). Block = 32 rows x 64 cols,
// 4 waves = k-splits {192,192,192,224-pad}; A direct-global + rotation
// prefetch; 6-product order; epilogue LDS reduce (+bias) -> b-major I0T.
// FP chains bit-identical to R10 (passed absmax 0).
// ---------------------------------------------------------------------------
__global__ __launch_bounds__(256, 2) void gemm0_kernel(
    const float* __restrict__ X, const short* __restrict__ W0p,
    const float* __restrict__ b0, float* __restrict__ I0T) {
  __shared__ float red[4][32][68];               // 34.8 KB wave-partials

  const int tid = threadIdx.x;
  const int r0  = blockIdx.x * 32;
  const int wid = tid >> 6;                      // wave 0..3 = k-split
  const int l   = tid & 63;
  const int lr  = l & 15;                        // frag row/col lane
  const int lk  = l >> 4;                        // frag k-octet lane

  const int kbeg = wid * 192;
  const int ccnt = (wid < 3) ? 6 : 7;            // last: 208 real k + 16 pad

  f32x4 acc[2][4];
#pragma unroll
  for (int rt = 0; rt < 2; ++rt)
#pragma unroll
    for (int ct = 0; ct < 4; ++ct) acc[rt][ct] = f32x4{0.f, 0.f, 0.f, 0.f};

  const float*  xr0 = X + (size_t)(r0 + lr) * NIN;
  const float*  xr1 = xr0 + 16 * NIN;
  const short8* wp8 = (const short8*)W0p;        // packed layout

  // ---- prologue: A-load chunk 0
  float4 cxa0, cxb0, cxa1, cxb1;
  {
    const int k0 = kbeg + lk * 8;
    if (k0 < NIN) {
      cxa0 = *(const float4*)(xr0 + k0);
      cxb0 = *(const float4*)(xr0 + k0 + 4);
      cxa1 = *(const float4*)(xr1 + k0);
      cxb1 = *(const float4*)(xr1 + k0 + 4);
    } else {
      cxa0 = cxb0 = cxa1 = cxb1 = float4{0.f, 0.f, 0.f, 0.f};
    }
  }

  for (int c = 0; c < ccnt; ++c) {
    const int kb = kbeg + c * 32;
    const int g  = (kbeg >> 5) + c;              // global 32-k chunk 0..24
    const bool more = (c + 1 < ccnt);

    // ---- issue next chunk's A-loads (HBM latency hides under this chunk)
    float4 nxa0, nxb0, nxa1, nxb1;
    if (more) {
      const int k0n = kb + 32 + lk * 8;
      if (k0n < NIN) {
        nxa0 = *(const float4*)(xr0 + k0n);
        nxb0 = *(const float4*)(xr0 + k0n + 4);
        nxa1 = *(const float4*)(xr1 + k0n);
        nxb1 = *(const float4*)(xr1 + k0n + 4);
      } else {
        nxa0 = nxb0 = nxa1 = nxb1 = float4{0.f, 0.f, 0.f, 0.f};
      }
    }

    // ---- batch-issue this chunk's 12 B-loads (packed, fully coalesced)
    short8 cb[4][3];
#pragma unroll
    for (int ct = 0; ct < 4; ++ct) {
#pragma unroll
      for (int p = 0; p < 3; ++p)
        cb[ct][p] = wp8[(size_t)((g * 3 + p) * 4 + ct) * 64 + l];
    }

    // ---- convert this chunk's A to bf16x3 fragments (overlaps B latency)
    short8 a0[3], a1[3];
    {
      float xs0[8] = {cxa0.x, cxa0.y, cxa0.z, cxa0.w, cxb0.x, cxb0.y, cxb0.z, cxb0.w};
      float xs1[8] = {cxa1.x, cxa1.y, cxa1.z, cxa1.w, cxb1.x, cxb1.y, cxb1.z, cxb1.w};
#pragma unroll
      for (int e = 0; e < 8; ++e) {
        float x  = xs0[e];
        short h0 = bf16_rne(x);   float rr1 = x - bf16_val(h0);
        short h1 = bf16_rne(rr1); float rr2 = rr1 - bf16_val(h1);
        a0[0][e] = h0; a0[1][e] = h1; a0[2][e] = bf16_rne(rr2);
        x  = xs1[e];
        h0 = bf16_rne(x);   rr1 = x - bf16_val(h0);
        h1 = bf16_rne(rr1); rr2 = rr1 - bf16_val(h1);
        a1[0][e] = h0; a1[1][e] = h1; a1[2][e] = bf16_rne(rr2);
      }
    }

    // ---- MFMA: 2 row-tiles x 4 col-tiles x 6 products (R10 order)
#pragma unroll
    for (int ct = 0; ct < 4; ++ct) {
      {
        f32x4 a = acc[0][ct];
        a = __builtin_amdgcn_mfma_f32_16x16x32_bf16(a0[2], cb[ct][0], a, 0, 0, 0);
        a = __builtin_amdgcn_mfma_f32_16x16x32_bf16(a0[0], cb[ct][2], a, 0, 0, 0);
        a = __builtin_amdgcn_mfma_f32_16x16x32_bf16(a0[1], cb[ct][1], a, 0, 0, 0);
        a = __builtin_amdgcn_mfma_f32_16x16x32_bf16(a0[1], cb[ct][0], a, 0, 0, 0);
        a = __builtin_amdgcn_mfma_f32_16x16x32_bf16(a0[0], cb[ct][1], a, 0, 0, 0);
        a = __builtin_amdgcn_mfma_f32_16x16x32_bf16(a0[0], cb[ct][0], a, 0, 0, 0);
        acc[0][ct] = a;
      }
      {
        f32x4 a = acc[1][ct];
        a = __builtin_amdgcn_mfma_f32_16x16x32_bf16(a1[2], cb[ct][0], a, 0, 0, 0);
        a = __builtin_amdgcn_mfma_f32_16x16x32_bf16(a1[0], cb[ct][2], a, 0, 0, 0);
        a = __builtin_amdgcn_mfma_f32_16x16x32_bf16(a1[1], cb[ct][1], a, 0, 0, 0);
        a = __builtin_amdgcn_mfma_f32_16x16x32_bf16(a1[1], cb[ct][0], a, 0, 0, 0);
        a = __builtin_amdgcn_mfma_f32_16x16x32_bf16(a1[0], cb[ct][1], a, 0, 0, 0);
        a = __builtin_amdgcn_mfma_f32_16x16x32_bf16(a1[0], cb[ct][0], a, 0, 0, 0);
        acc[1][ct] = a;
      }
    }

    // ---- rotate prefetched A into current
    if (more) {
      cxa0 = nxa0; cxb0 = nxb0; cxa1 = nxa1; cxb1 = nxb1;
    }
  }

  // ---- epilogue: wave-partials -> LDS  (C/D: col=l&15, row=(l>>4)*4+r)
#pragma unroll
  for (int rt = 0; rt < 2; ++rt)
#pragma unroll
    for (int ct = 0; ct < 4; ++ct)
#pragma unroll
      for (int r = 0; r < 4; ++r)
        red[wid][rt * 16 + lk * 4 + r][ct * 16 + lr] = acc[rt][ct][r];
  __syncthreads();

  // ---- reduce 4 partials + bias (R10 order), write b-major I0T
  const int t0  = r0 >> 8;
  const int bb0 = r0 & 255;
  for (int idx = tid; idx < 32 * 16; idx += 256) {
    int row = idx >> 4, q = idx & 15;
    float4 v  = *(const float4*)&red[0][row][q * 4];
    float4 u1 = *(const float4*)&red[1][row][q * 4];
    float4 u2 = *(const float4*)&red[2][row][q * 4];
    float4 u3 = *(const float4*)&red[3][row][q * 4];
    v.x += u1.x; v.y += u1.y; v.z += u1.z; v.w += u1.w;
    v.x += u2.x; v.y += u2.y; v.z += u2.z; v.w += u2.w;
    v.x += u3.x; v.y += u3.y; v.z += u3.z; v.w += u3.w;
    float4 bv = ((const float4*)b0)[q];
    v.x += bv.x; v.y += bv.y; v.z += bv.z; v.w += bv.w;
    ((float4*)I0T)[((size_t)(bb0 + row) * T_STEPS + t0) * 16 + q] = v;
  }
}

// ---------------------------------------------------------------------------
// Kernel 2: one block per batch element (R9's lean fused body, measured).
// ---------------------------------------------------------------------------
__global__ __launch_bounds__(256) void fused_kernel(
    const float* __restrict__ I0T,
    const float* __restrict__ W1, const float* __restrict__ b1,
    const float* __restrict__ W2, const float* __restrict__ b2,
    float* __restrict__ out) {
  __shared__ float bufA[112][68];
  __shared__ float sW1t[64][68];
  __shared__ float sW2[N2][68];
  __shared__ float sI2[T_STEPS][N2];

  const int b   = blockIdx.x;
  const int tid = threadIdx.x;
  const int j   = tid & 63;
  const int tq  = tid >> 6;
  float* outSpk = out;
  float* laySpk = out + T_STEPS * BATCH * N2;

  {
    const float4* src = (const float4*)I0T + (size_t)b * (T_STEPS * 16);
    for (int idx = tid; idx < T_STEPS * 16; idx += 256) {
      float4 v = src[idx];
      int t = idx >> 4, j4 = idx & 15;
      *(float4*)&bufA[t][j4 * 4] = v;
    }
  }
  __syncthreads();

  if (tq == 0) {
    float v = 0.0f;
#pragma unroll
    for (int g = 0; g < 4; ++g) {
      float ic[25];
#pragma unroll
      for (int i = 0; i < 25; ++i) ic[i] = bufA[g * 25 + i][j];
#pragma unroll
      for (int i = 0; i < 25; ++i) {
        v = v + 0.05f * ((0.0f - v) + ic[i]);
        float z = (v > 1.0f) ? 1.0f : 0.0f;
        v -= z;
        ic[i] = z;
      }
#pragma unroll
      for (int i = 0; i < 25; ++i) bufA[g * 25 + i][j] = ic[i];
    }
  } else {
    for (int idx = tid - 64; idx < 64 * 16; idx += 192) {
      int i = idx >> 4, jv = idx & 15;
      float4 wv = *(const float4*)(W1 + (size_t)i * 64 + jv * 4);
      sW1t[jv * 4 + 0][i] = wv.x;
      sW1t[jv * 4 + 1][i] = wv.y;
      sW1t[jv * 4 + 2][i] = wv.z;
      sW1t[jv * 4 + 3][i] = wv.w;
    }
    for (int idx = tid - 64; idx < N2 * 16; idx += 192) {
      int o = idx >> 4, jv = idx & 15;
      *(float4*)&sW2[o][jv * 4] = *(const float4*)(W2 + (size_t)o * 64 + jv * 4);
    }
  }
  __syncthreads();

  for (int idx = tid; idx < T_STEPS * 16; idx += 256) {
    int t = idx >> 4, jv = idx & 15;
    *(float4*)(laySpk + (size_t)t * CHUNK + b * 64 + jv * 4) =
        *(const float4*)&bufA[t][jv * 4];
  }

  const int iq = tid & 15;
  const int ts = tid >> 4;
  float g1[4][7];
  {
    float4 bias = *(const float4*)(b1 + iq * 4);
#pragma unroll
    for (int tt = 0; tt < 7; ++tt) {
      g1[0][tt] = bias.x; g1[1][tt] = bias.y; g1[2][tt] = bias.z; g1[3][tt] = bias.w;
    }
#pragma unroll
    for (int jq = 0; jq < 16; ++jq) {
      float4 zv4[7];
#pragma unroll
      for (int tt = 0; tt < 7; ++tt)
        zv4[tt] = *(const float4*)&bufA[ts * 7 + tt][jq * 4];
      float4 w4[4];
#pragma unroll
      for (int e = 0; e < 4; ++e)
        w4[e] = *(const float4*)&sW1t[jq * 4 + e][iq * 4];
#pragma unroll
      for (int e = 0; e < 4; ++e) {
#pragma unroll
        for (int tt = 0; tt < 7; ++tt) {
          float zv = ((const float*)&zv4[tt])[e];
          g1[0][tt] = fmaf(zv, w4[e].x, g1[0][tt]);
          g1[1][tt] = fmaf(zv, w4[e].y, g1[1][tt]);
          g1[2][tt] = fmaf(zv, w4[e].z, g1[2][tt]);
          g1[3][tt] = fmaf(zv, w4[e].w, g1[3][tt]);
        }
      }
    }
  }
  __syncthreads();
#pragma unroll
  for (int tt = 0; tt < 7; ++tt) {
    float4 o = {g1[0][tt], g1[1][tt], g1[2][tt], g1[3][tt]};
    *(float4*)&bufA[ts * 7 + tt][iq * 4] = o;
  }
  __syncthreads();

  if (tq == 0) {
    float v = 0.0f;
#pragma unroll
    for (int g = 0; g < 4; ++g) {
      float ic[25];
#pragma unroll
      for (int i = 0; i < 25; ++i) ic[i] = bufA[g * 25 + i][j];
#pragma unroll
      for (int i = 0; i < 25; ++i) {
        v = v + 0.05f * ((0.0f - v) + ic[i]);
        float z = (v > 1.0f) ? 1.0f : 0.0f;
        v -= z;
        ic[i] = z;
      }
#pragma unroll
      for (int i = 0; i < 25; ++i) bufA[g * 25 + i][j] = ic[i];
    }
  }
  __syncthreads();

  for (int idx = tid; idx < T_STEPS * 16; idx += 256) {
    int t = idx >> 4, jv = idx & 15;
    *(float4*)(laySpk + (size_t)t * CHUNK + BATCH * N0 + b * 64 + jv * 4) =
        *(const float4*)&bufA[t][jv * 4];
  }

  for (int idx = tid; idx < T_STEPS * N2; idx += 256) {
    int t = idx / N2, o = idx % N2;
    float a = b2[o];
#pragma unroll
    for (int jq = 0; jq < 16; ++jq) {
      float4 z = *(const float4*)&bufA[t][jq * 4];
      float4 wv = *(const float4*)&sW2[o][jq * 4];
      a += z.x * wv.x;
      a += z.y * wv.y;
      a += z.z * wv.z;
      a += z.w * wv.w;
    }
    sI2[t][o] = a;
  }
  __syncthreads();

  if (tid < N2) {
    float v = 0.0f;
#pragma unroll
    for (int g = 0; g < 4; ++g) {
      float ic[25];
#pragma unroll
      for (int i = 0; i < 25; ++i) ic[i] = sI2[g * 25 + i][tid];
#pragma unroll
      for (int i = 0; i < 25; ++i) {
        v = v + 0.05f * ((0.0f - v) + ic[i]);
        float z = (v > 1.0f) ? 1.0f : 0.0f;
        v -= z;
        ic[i] = z;
      }
#pragma unroll
      for (int i = 0; i < 25; ++i) sI2[g * 25 + i][tid] = ic[i];
    }
  }
  __syncthreads();

  for (int idx = tid; idx < T_STEPS * N2; idx += 256) {
    int t = idx / N2, o = idx % N2;
    float z = sI2[t][o];
    outSpk[(size_t)t * (BATCH * N2) + b * N2 + o] = z;
    laySpk[(size_t)t * CHUNK + BATCH * (N0 + N1) + b * N2 + o] = z;
  }
}

extern "C" void kernel_launch(void* const* d_in, const int* in_sizes, int n_in,
                              void* d_out, int out_size, void* d_ws, size_t ws_size,
                              hipStream_t stream) {
  const float* inp = (const float*)d_in[0];
  const float* W0  = (const float*)d_in[1];
  const float* b0  = (const float*)d_in[2];
  const float* W1  = (const float*)d_in[3];
  const float* b1  = (const float*)d_in[4];
  const float* W2  = (const float*)d_in[5];
  const float* b2  = (const float*)d_in[6];

  float* I0T = (float*)d_ws;                 // 6.55 MB, b-major [b][t][j]
  short* W0p = (short*)(I0T + I0ELEMS);      // 300 KB packed bf16x3 fragments

  prep_w0_pack<<<dim3(600), dim3(256), 0, stream>>>(W0, W0p);
  gemm0_kernel<<<dim3(800), dim3(256), 0, stream>>>(inp, W0p, b0, I0T);
  fused_kernel<<<dim3(BATCH), dim3(256), 0, stream>>>(I0T, W1, b1, W2, b2,
                                                      (float*)d_out);
}